// Round 2
// baseline (384.189 us; speedup 1.0000x reference)
//
#include <hip/hip_runtime.h>
#include <math.h>

#define C_DIM 128
#define SHD   16
#define HID   128
#define MIN_D 64
#define OUT_PER_NODE 2048   // C * (1+3+5+7)
#define BLK   256
#define SCAN_T 1024
#define EBLK  64            // edges per fused block

typedef __attribute__((ext_vector_type(8))) short bf16x8;
typedef __attribute__((ext_vector_type(4))) float f32x4;

__device__ __forceinline__ unsigned f2bf_u(float x) {
    unsigned u = __builtin_bit_cast(unsigned, x);
    return (u + 0x7fffu + ((u >> 16) & 1u)) >> 16;   // round-to-nearest-even
}
__device__ __forceinline__ short f2bf(float x) { return (short)f2bf_u(x); }
__device__ __forceinline__ unsigned packbf2(float a, float b) {
    return f2bf_u(a) | (f2bf_u(b) << 16);
}
__device__ __forceinline__ float bf2f(unsigned h) {
    return __builtin_bit_cast(float, h << 16);
}

// ---------------- prep: histogram + weight conversion (fused) ----------------
// w2t column permutation: wave w / tile j / lane m16 owns output channel
// 64*w + 4*m16 + j, so Phase B can store a contiguous uint2 per edge per lane.
__global__ void prep_kernel(const int* __restrict__ dst, int* counts, int E,
                            const float* __restrict__ W1, const float* __restrict__ W2,
                            short* __restrict__ w1t, short* __restrict__ w2t,
                            int HB) {
    int b = blockIdx.x;
    int t = threadIdx.x;
    if (b < HB) {
        int i = b * BLK + t;
        if (i < E) atomicAdd(&counts[dst[i]], 1);
    } else {
        int i = (b - HB) * BLK + t;
        if (i < MIN_D * HID) {
            int n = i >> 6, k = i & 63;
            w1t[i] = f2bf(W1[k * HID + n] * 0.125f);
        } else if (i < MIN_D * HID + HID * 512) {
            int j = i - MIN_D * HID;
            int p = j >> 7, ks = j & 127;
            int nt = p >> 4, m16 = p & 15;
            int jcol = 64 * (nt >> 2) + 4 * m16 + (nt & 3);
            int ka   = (2 * (ks >> 5) + (ks & 1)) * 16 + ((ks >> 1) & 15);
            w2t[j] = f2bf(W2[ka * 512 + jcol] * 0.0883883476483184f);
        }
    }
}

__global__ __launch_bounds__(SCAN_T)
void scan_kernel(const int* __restrict__ counts, int* row_ptr, int* cursor, int n) {
    const int t = threadIdx.x;
    const int per = (n + SCAN_T - 1) / SCAN_T;
    int lp[16];
    int base = t * per;
    int sum = 0;
    for (int i = 0; i < per && i < 16; ++i) {
        int idx = base + i;
        int v = (idx < n) ? counts[idx] : 0;
        lp[i] = sum;
        sum += v;
    }
    __shared__ int sbuf[SCAN_T];
    sbuf[t] = sum;
    __syncthreads();
    for (int off = 1; off < SCAN_T; off <<= 1) {
        int v = (t >= off) ? sbuf[t - off] : 0;
        __syncthreads();
        sbuf[t] += v;
        __syncthreads();
    }
    int excl = (t == 0) ? 0 : sbuf[t - 1];
    for (int i = 0; i < per && i < 16; ++i) {
        int idx = base + i;
        if (idx < n) {
            int rp = excl + lp[i];
            row_ptr[idx] = rp;
            cursor[idx]  = rp;
        }
    }
    if (t == SCAN_T - 1) row_ptr[n] = sbuf[SCAN_T - 1];
}

__global__ void scatter_kernel(const int* __restrict__ dst, const int* __restrict__ src,
                               int* cursor, int2* es_list, int E) {
    int i = blockIdx.x * blockDim.x + threadIdx.x;
    if (i < E) {
        int pos = atomicAdd(&cursor[dst[i]], 1);
        es_list[pos] = make_int2(i, src[i]);
    }
}

// ---------------- segment descriptors + zero-fill for split/empty nodes ------
// seg word: node(16b) | s(6b @16) | e(7b @22) | full(1b @31); s,e block-local.
__global__ __launch_bounds__(BLK)
void seg_zero_kernel(const int* __restrict__ row_ptr, unsigned* __restrict__ seg,
                     int* __restrict__ segcnt, float* __restrict__ out, int n_dst) {
    const int n = blockIdx.x;
    const int t = threadIdx.x;
    const int rb = row_ptr[n], re = row_ptr[n + 1];
    if (rb == re) {   // no edges: row must be zero
        float4 z = make_float4(0.f, 0.f, 0.f, 0.f);
        float4* op = (float4*)(out + (size_t)n * OUT_PER_NODE);
        for (int i = t; i < OUT_PER_NODE / 4; i += BLK) op[i] = z;
        return;
    }
    const int b0 = rb >> 6, b1 = (re - 1) >> 6;
    const bool full = (b0 == b1);
    if (t == 0) {
        for (int b = b0; b <= b1; ++b) {
            int s = rb - b * EBLK; if (s < 0) s = 0;
            int e = re - b * EBLK; if (e > EBLK) e = EBLK;
            int idx = atomicAdd(&segcnt[b], 1);
            if (idx < EBLK)   // defensive: impossible by construction
                seg[(size_t)b * EBLK + idx] =
                    (unsigned)n | ((unsigned)s << 16) | ((unsigned)e << 22)
                                | (full ? (1u << 31) : 0u);
        }
    }
    if (!full) {      // split node: zero row, partial segments atomicAdd into it
        float4 z = make_float4(0.f, 0.f, 0.f, 0.f);
        float4* op = (float4*)(out + (size_t)n * OUT_PER_NODE);
        for (int i = t; i < OUT_PER_NODE / 4; i += BLK) op[i] = z;
    }
}

// ---------------- fused MLP + tensor-product + segment-sum -------------------
template<int L>
__device__ __forceinline__ void tp_seg(
    const float* __restrict__ src_features,
    const float* __restrict__ edge_sh,
    const unsigned* tp_lds,
    const int2* __restrict__ es_list,
    float* __restrict__ out,
    int n, int tq, int p0, int s, int e, bool full)
{
    constexpr int D = 2 * L + 1;
    constexpr int SHOFF = L * L;
    const int c0 = (2 * tq) & 127;

    float accA[D], accB[D];
#pragma unroll
    for (int m = 0; m < D; ++m) { accA[m] = 0.f; accB[m] = 0.f; }

    int i = s;
    for (; i + 4 <= e; i += 4) {
        int2 es[4];
#pragma unroll
        for (int k = 0; k < 4; ++k) es[k] = es_list[p0 + i + k];
        unsigned tp2[4]; float2 x[4]; float sh[4][D];
#pragma unroll
        for (int k = 0; k < 4; ++k) {
            tp2[k] = tp_lds[(i + k) * 256 + tq];
            x[k]   = *(const float2*)&src_features[(size_t)es[k].y * C_DIM + c0];
            const float* shp = &edge_sh[(size_t)es[k].x * SHD + SHOFF];
#pragma unroll
            for (int m = 0; m < D; ++m) sh[k][m] = shp[m];
        }
#pragma unroll
        for (int k = 0; k < 4; ++k) {
            float wx0 = bf2f(tp2[k] & 0xffffu) * x[k].x;
            float wx1 = bf2f(tp2[k] >> 16)     * x[k].y;
#pragma unroll
            for (int m = 0; m < D; ++m) {
                accA[m] += wx0 * sh[k][m];
                accB[m] += wx1 * sh[k][m];
            }
        }
    }
    for (; i < e; ++i) {
        int2 es = es_list[p0 + i];
        unsigned tp2 = tp_lds[i * 256 + tq];
        float2 x = *(const float2*)&src_features[(size_t)es.y * C_DIM + c0];
        const float* shp = &edge_sh[(size_t)es.x * SHD + SHOFF];
        float wx0 = bf2f(tp2 & 0xffffu) * x.x;
        float wx1 = bf2f(tp2 >> 16)     * x.y;
#pragma unroll
        for (int m = 0; m < D; ++m) {
            float shv = shp[m];
            accA[m] += wx0 * shv;
            accB[m] += wx1 * shv;
        }
    }

    float* op = out + (size_t)n * OUT_PER_NODE + 128 * SHOFF + c0 * D;
    if (full) {
#pragma unroll
        for (int m = 0; m < D; ++m) op[m] = accA[m];
#pragma unroll
        for (int m = 0; m < D; ++m) op[D + m] = accB[m];
    } else {
#pragma unroll
        for (int m = 0; m < D; ++m) atomicAdd(&op[m], accA[m]);
#pragma unroll
        for (int m = 0; m < D; ++m) atomicAdd(&op[D + m], accB[m]);
    }
}

// 512 threads / 8 waves per 64-edge block. LDS = 64KB tp + 16KB h = 80KB
// -> 2 blocks/CU (LDS-limited). Phase A: wave pair (w,w+4) shares m-tile w&3,
// splits hidden cols. Phase B: wave w owns n-tiles 4w..4w+3 over all 4 m-tiles;
// stores contiguous uint2 per edge into tp_lds (dword d holds channels
// (2*(d&63), +1) of l = d>>6). Phase TP: 2 x 256-thread halves, alternating
// dst-segments.
__global__ __launch_bounds__(512, 4)
void fused_kernel(const float* __restrict__ edge_emb,
                  const short* __restrict__ w1t,
                  const short* __restrict__ w2t,
                  const float* __restrict__ src_features,
                  const float* __restrict__ edge_sh,
                  const int2* __restrict__ es_list,
                  const unsigned* __restrict__ seg,
                  const int* __restrict__ segcnt,
                  float* __restrict__ out,
                  int E)
{
    const int t    = threadIdx.x;
    const int lane = t & 63;
    const int w    = t >> 6;        // 0..7
    const int m16  = lane & 15;
    const int q    = lane >> 4;
    const int b    = blockIdx.x;
    const int p0   = b * EBLK;

    __shared__ __align__(16) unsigned tp_lds[EBLK * 256];  // 64 KB
    __shared__ __align__(16) unsigned hb[EBLK * 64];       // 16 KB, XOR-swizzled

    union CVT { unsigned u[4]; bf16x8 v; };

    // ---- Phase A: layer-1 MFMA ----
    {
        const int mt = w & 3;
        const int uh = w >> 2;
        const int prow = p0 + mt * 16 + m16;
        bf16x8 a[2];
        if (prow < E) {
            const int eid = es_list[prow].x;
            const float* rp = &edge_emb[(size_t)eid * MIN_D];
#pragma unroll
            for (int ks = 0; ks < 2; ++ks) {
                float4 v0 = *(const float4*)&rp[ks * 32 + q * 8];
                float4 v1 = *(const float4*)&rp[ks * 32 + q * 8 + 4];
                CVT c;
                c.u[0] = packbf2(v0.x, v0.y);
                c.u[1] = packbf2(v0.z, v0.w);
                c.u[2] = packbf2(v1.x, v1.y);
                c.u[3] = packbf2(v1.z, v1.w);
                a[ks] = c.v;
            }
        } else {
            CVT c; c.u[0] = c.u[1] = c.u[2] = c.u[3] = 0u;
            a[0] = c.v; a[1] = c.v;
        }
#pragma unroll
        for (int ui = 0; ui < 2; ++ui) {
            const int u2 = 2 * uh + ui;
            f32x4 c0 = {0.f, 0.f, 0.f, 0.f}, c1 = {0.f, 0.f, 0.f, 0.f};
#pragma unroll
            for (int ks = 0; ks < 2; ++ks) {
                bf16x8 b0 = *(const bf16x8*)&w1t[((2 * u2)     * 16 + m16) * MIN_D + ks * 32 + q * 8];
                bf16x8 b1 = *(const bf16x8*)&w1t[((2 * u2 + 1) * 16 + m16) * MIN_D + ks * 32 + q * 8];
                c0 = __builtin_amdgcn_mfma_f32_16x16x32_bf16(a[ks], b0, c0, 0, 0, 0);
                c1 = __builtin_amdgcn_mfma_f32_16x16x32_bf16(a[ks], b1, c1, 0, 0, 0);
            }
#pragma unroll
            for (int r = 0; r < 4; ++r) {
                const int row = mt * 16 + q * 4 + r;
                float z0 = c0[r], z1 = c1[r];
                float h0 = z0 / (1.f + __expf(-z0));
                float h1 = z1 / (1.f + __expf(-z1));
                // dword-index XOR swizzle ((row&7)<<2) keeps 16B groups intact,
                // kills the stride-256B bank conflict on Phase-B ds_read_b128
                hb[(row * 64 + 16 * u2 + m16) ^ ((row & 7) << 2)] = packbf2(h0, h1);
            }
        }
    }

    // layer-2 B-frags loaded before barrier (overlaps other waves' Phase A)
    bf16x8 B[4][4];
#pragma unroll
    for (int j = 0; j < 4; ++j)
#pragma unroll
        for (int ks = 0; ks < 4; ++ks)
            B[j][ks] = *(const bf16x8*)&w2t[((4 * w + j) * 16 + m16) * HID + ks * 32 + q * 8];

    __syncthreads();

    // ---- Phase B: layer-2 MFMA -> tp_lds (uint2 per edge per lane) ----
    {
        const int d0 = 64 * (w >> 1) + 32 * (w & 1) + 2 * m16;
#pragma unroll
        for (int mt = 0; mt < 4; ++mt) {
            const int row = mt * 16 + m16;
            bf16x8 av[4];
#pragma unroll
            for (int ks = 0; ks < 4; ++ks)
                av[ks] = *(const bf16x8*)&hb[(row * 64 + ks * 16 + q * 4) ^ ((row & 7) << 2)];
            f32x4 acc[4];
#pragma unroll
            for (int j = 0; j < 4; ++j) acc[j] = (f32x4){0.f, 0.f, 0.f, 0.f};
#pragma unroll
            for (int ks = 0; ks < 4; ++ks)
#pragma unroll
                for (int j = 0; j < 4; ++j)
                    acc[j] = __builtin_amdgcn_mfma_f32_16x16x32_bf16(av[ks], B[j][ks], acc[j], 0, 0, 0);
#pragma unroll
            for (int r = 0; r < 4; ++r) {
                const int el = mt * 16 + q * 4 + r;
                uint2 u;
                u.x = packbf2(acc[0][r], acc[1][r]);   // channels 4g, 4g+1
                u.y = packbf2(acc[2][r], acc[3][r]);   // channels 4g+2, 4g+3
                *(uint2*)&tp_lds[el * 256 + d0] = u;
            }
        }
    }

    __syncthreads();

    // ---- Phase TP: two 256-thread halves, alternating segments ----
    {
        const int half = w >> 2;
        const int tq   = t & 255;
        const int l    = tq >> 6;           // wave-uniform
        const int nseg = segcnt[b];
        for (int k = half; k < nseg; k += 2) {
            const unsigned sw = seg[(size_t)b * EBLK + k];
            const int  n    = (int)(sw & 0xffffu);
            const int  s    = (int)((sw >> 16) & 63u);
            const int  e    = (int)((sw >> 22) & 127u);
            const bool full = (sw >> 31) != 0u;
            if (l == 0)      tp_seg<0>(src_features, edge_sh, tp_lds, es_list, out, n, tq, p0, s, e, full);
            else if (l == 1) tp_seg<1>(src_features, edge_sh, tp_lds, es_list, out, n, tq, p0, s, e, full);
            else if (l == 2) tp_seg<2>(src_features, edge_sh, tp_lds, es_list, out, n, tq, p0, s, e, full);
            else             tp_seg<3>(src_features, edge_sh, tp_lds, es_list, out, n, tq, p0, s, e, full);
        }
    }
}

// ---------------- launch ----------------
extern "C" void kernel_launch(void* const* d_in, const int* in_sizes, int n_in,
                              void* d_out, int out_size, void* d_ws, size_t ws_size,
                              hipStream_t stream) {
    const float* src_features = (const float*)d_in[0];
    const float* edge_sh      = (const float*)d_in[1];
    const float* edge_emb     = (const float*)d_in[2];
    const float* W1           = (const float*)d_in[3];
    const float* W2           = (const float*)d_in[4];
    const int*   src          = (const int*)d_in[5];
    const int*   dst          = (const int*)d_in[6];

    const int E     = in_sizes[5];
    const int N_DST = out_size / OUT_PER_NODE;
    const int NB    = (E + EBLK - 1) / EBLK;

    // ws layout (16B-aligned pieces first)
    char* p = (char*)d_ws;
    short* w1t     = (short*)p;    p += MIN_D * HID * 2;          // 16 KB
    short* w2t     = (short*)p;    p += HID * 512 * 2;            // 128 KB
    int2* es_list  = (int2*)p;     p += (size_t)E * 8;
    unsigned* seg  = (unsigned*)p; p += (size_t)NB * EBLK * 4;    // ~400 KB
    int* counts    = (int*)p;      p += 16384 * 4;
    int* row_ptr   = (int*)p;      p += 16384 * 4;
    int* cursor    = (int*)p;      p += 16384 * 4;
    int* segcnt    = (int*)p;      p += (size_t)NB * 4;

    const int HB = (E + BLK - 1) / BLK;
    const int CB = (MIN_D * HID + HID * 512 + BLK - 1) / BLK;

    (void)hipMemsetAsync(counts, 0, (size_t)N_DST * 4, stream);
    (void)hipMemsetAsync(segcnt, 0, (size_t)NB * 4, stream);
    prep_kernel<<<HB + CB, BLK, 0, stream>>>(dst, counts, E, W1, W2, w1t, w2t, HB);
    scan_kernel<<<1, SCAN_T, 0, stream>>>(counts, row_ptr, cursor, N_DST);
    scatter_kernel<<<(E + 255) / 256, 256, 0, stream>>>(dst, src, cursor, es_list, E);
    seg_zero_kernel<<<N_DST, BLK, 0, stream>>>(row_ptr, seg, segcnt, (float*)d_out, N_DST);
    fused_kernel<<<NB, 512, 0, stream>>>(edge_emb, w1t, w2t, src_features, edge_sh,
                                         es_list, seg, segcnt, (float*)d_out, E);
}